// Round 19
// baseline (153.193 us; speedup 1.0000x reference)
//
#include <hip/hip_runtime.h>
#include <hip/hip_bf16.h>
#include <stdint.h>

#define H_NUM 16
#define S_LEN 2048
#define D_DIM 128
#define WIN   512
#define NWG   256                       // 16 heads x 16 q-groups(128 rows)
#define LOG2E 1.4426950408889634f

typedef __attribute__((ext_vector_type(8)))  _Float16 half8;
typedef __attribute__((ext_vector_type(2)))  __fp16   fp16x2;
typedef __attribute__((ext_vector_type(16))) float f32x16;
typedef __attribute__((ext_vector_type(4)))  unsigned int uint4v;

static __device__ __forceinline__ uint32_t pk16(float a, float b) {
    fp16x2 t = __builtin_amdgcn_cvt_pkrtz(a, b);
    return __builtin_bit_cast(uint32_t, t);
}
static __device__ __forceinline__ float fexp2(float x) {
#if __has_builtin(__builtin_amdgcn_exp2f)
    return __builtin_amdgcn_exp2f(x);
#else
    return exp2f(x);
#endif
}

// ================= CHAMPION (r14, 32.6us) — unchanged, writes d_out ==========
__global__ __launch_bounds__(512, 2) void swa_fwd(
    const float* __restrict__ Q, const float* __restrict__ K,
    const float* __restrict__ V, float* __restrict__ O)
{
    __shared__ __align__(16) char arena[71680];
    char* ksL = arena;
    char* vsL = arena + 16384;
    char* ksH = arena + 32768;
    char* vsH = arena + 49152;
    float* mrg_o  = (float*)arena;
    float* mrg_ml = (float*)(arena + 69632);

    int bid = blockIdx.x;
    int wid = ((bid & 7) << 5) | (bid >> 3);
    int h    = wid >> 4;
    int q0wg = (wid & 15) << 7;

    int tid  = threadIdx.x;
    int wv   = tid >> 6;
    int lane = tid & 63;
    int qn = lane & 31;
    int hi = lane >> 5;
    int qsel = wv & 3;
    int hseg = wv >> 2;
    int q0 = q0wg + qsel * 32;

    const float* Qh = Q + ((size_t)h << 18);
    const float* Kg = K + ((size_t)h << 18);
    const float* Vg = V + ((size_t)h << 18);
    float*       Oh = O + ((size_t)h << 18);

    int tK_r = tid >> 4;
    int tK_d = (tid & 15) * 8;
    int tK_byte = tK_r * 256 + (((tid & 15) * 16) ^ ((tK_r & 7) << 4));
    int tV_d = (tid >> 4) * 4;
    int tV_s = (tid & 15) * 2;
    int tV_byte = (tV_s >> 3) * 2048 + tV_d * 16 + (tV_s & 7) * 2;

#define K_LOAD(A0, A1, KB_) do {                                               \
        const float* sp_ = Kg + ((size_t)((KB_) + tK_r) << 7) + tK_d;          \
        A0 = *reinterpret_cast<const float4*>(sp_);                            \
        A1 = *reinterpret_cast<const float4*>(sp_ + 4); } while (0)
#define K_WRITE(KS, BUF, A0, A1) do {                                          \
        uint4v u_;                                                             \
        u_[0] = pk16(A0.x, A0.y); u_[1] = pk16(A0.z, A0.w);                    \
        u_[2] = pk16(A1.x, A1.y); u_[3] = pk16(A1.z, A1.w);                    \
        *reinterpret_cast<uint4v*>((KS) + (BUF) * 8192 + tK_byte) = u_; } while (0)
#define V_LOAD(A0, A1, KB_) do {                                               \
        const float* sp_ = Vg + ((size_t)((KB_) + tV_s) << 7) + tV_d;          \
        A0 = *reinterpret_cast<const float4*>(sp_);                            \
        A1 = *reinterpret_cast<const float4*>(sp_ + D_DIM); } while (0)
#define V_WRITE(VS, BUF, A0, A1) do {                                          \
        char* b_ = (VS) + (BUF) * 8192 + tV_byte;                              \
        *reinterpret_cast<uint32_t*>(b_)      = pk16(A0.x, A1.x);              \
        *reinterpret_cast<uint32_t*>(b_ + 16) = pk16(A0.y, A1.y);              \
        *reinterpret_cast<uint32_t*>(b_ + 32) = pk16(A0.z, A1.z);              \
        *reinterpret_cast<uint32_t*>(b_ + 48) = pk16(A0.w, A1.w); } while (0)

    half8 qa[8];
    const float* qrow = Qh + ((size_t)(q0 + qn) << 7) + hi * 8;
    #pragma unroll
    for (int c = 0; c < 8; ++c) {
        float4 a0 = *reinterpret_cast<const float4*>(qrow + c * 16);
        float4 a1 = *reinterpret_cast<const float4*>(qrow + c * 16 + 4);
        qa[c] = (half8){(_Float16)(a0.x * LOG2E), (_Float16)(a0.y * LOG2E),
                        (_Float16)(a0.z * LOG2E), (_Float16)(a0.w * LOG2E),
                        (_Float16)(a1.x * LOG2E), (_Float16)(a1.y * LOG2E),
                        (_Float16)(a1.z * LOG2E), (_Float16)(a1.w * LOG2E)};
    }

    f32x16 oacc[4];
    #pragma unroll
    for (int db = 0; db < 4; ++db)
        #pragma unroll
        for (int i = 0; i < 16; ++i) oacc[db][i] = 0.f;
    float m_s = -1e30f, l_s = 0.f;

    int kstart = q0wg - (WIN - 1);
    if (kstart < 0) kstart = 0;
    kstart &= ~31;
    int nt  = ((q0wg + 128) - kstart) >> 5;
    int nt0 = (nt + 1) >> 1;
    int ntH = nt - nt0;
    int iq   = q0 + qn;
    int w_ks = q0 - (WIN - 1);
    int w_ke = q0 + 32;

    {
        float4 a0, a1;
        K_LOAD(a0, a1, kstart);             K_WRITE(ksL, 0, a0, a1);
        K_LOAD(a0, a1, kstart + nt0 * 32);  K_WRITE(ksH, 0, a0, a1);
        V_LOAD(a0, a1, kstart);             V_WRITE(vsL, 0, a0, a1);
        V_LOAD(a0, a1, kstart + nt0 * 32);  V_WRITE(vsH, 0, a0, a1);
    }

    int my_cnt = hseg ? ntH : nt0;
    for (int it = 0; it < nt0; ++it) {
        int cur = it & 1, nxt = cur ^ 1;
        __syncthreads();

        bool hl = (it + 1 < nt0), hh = (it + 1 < ntH);
        float4 kl0, kl1, kh0, kh1;
        if (hl) K_LOAD(kl0, kl1, kstart + (it + 1) * 32);
        if (hh) K_LOAD(kh0, kh1, kstart + (nt0 + it + 1) * 32);

        int mt = (hseg ? nt0 : 0) + it;
        int kb = kstart + mt * 32;
        bool act = (it < my_cnt) && (kb < w_ke) && (kb + 32 > w_ks);
        const char* ksb = (hseg ? ksH : ksL) + cur * 8192;
        const char* vsb = (hseg ? vsH : vsL) + cur * 8192;

        f32x16 sacc;
        if (act) {
            #pragma unroll
            for (int i = 0; i < 16; ++i) sacc[i] = 0.f;
            int sw = (qn & 7) << 4;
            #pragma unroll
            for (int c = 0; c < 8; ++c) {
                half8 kh = *reinterpret_cast<const half8*>(
                    ksb + qn * 256 + ((c * 32 + hi * 16) ^ sw));
                sacc = __builtin_amdgcn_mfma_f32_32x32x16_f16(kh, qa[c], sacc, 0, 0, 0);
            }
        }

        if (hl) K_WRITE(ksL, nxt, kl0, kl1);
        if (hh) K_WRITE(ksH, nxt, kh0, kh1);
        float4 vl0, vl1, vh0, vh1;
        if (hl) V_LOAD(vl0, vl1, kstart + (it + 1) * 32);
        if (hh) V_LOAD(vh0, vh1, kstart + (nt0 + it + 1) * 32);

        if (act) {
            float p[16];
            bool fullt = (kb >= q0 - 480) && (kb <= q0 - 31);
            if (fullt) {
                #pragma unroll
                for (int r = 0; r < 16; ++r) p[r] = sacc[r];
            } else {
                #pragma unroll
                for (int r = 0; r < 16; ++r) {
                    int j = kb + (r & 3) + 8 * (r >> 2) + 4 * hi;
                    p[r] = ((j <= iq) && (j + WIN > iq)) ? sacc[r] : -1e30f;
                }
            }
            float t0 = fmaxf(fmaxf(p[0], p[1]), p[2]);
            float t1 = fmaxf(fmaxf(p[3], p[4]), p[5]);
            float t2 = fmaxf(fmaxf(p[6], p[7]), p[8]);
            float t3 = fmaxf(fmaxf(p[9], p[10]), p[11]);
            float t4 = fmaxf(fmaxf(p[12], p[13]), p[14]);
            float tm = fmaxf(fmaxf(fmaxf(t0, t1), fmaxf(t2, t3)), fmaxf(t4, p[15]));
            tm = fmaxf(tm, __shfl_xor(tm, 32));

            if (!__all(tm - m_s <= 11.5424f)) {
                float mn = fmaxf(m_s, tm);
                float scale = fexp2(m_s - mn);
                m_s = mn;
                l_s *= scale;
                #pragma unroll
                for (int r = 0; r < 16; ++r) {
                    float sr = __shfl(scale, (r & 3) + 8 * (r >> 2) + 4 * hi);
                    oacc[0][r] *= sr; oacc[1][r] *= sr;
                    oacc[2][r] *= sr; oacc[3][r] *= sr;
                }
            }
            #pragma unroll
            for (int r = 0; r < 16; ++r) p[r] = fexp2(p[r] - m_s);
            {
                float s0 = (p[0] + p[1]) + (p[2] + p[3]);
                float s1 = (p[4] + p[5]) + (p[6] + p[7]);
                float s2 = (p[8] + p[9]) + (p[10] + p[11]);
                float s3 = (p[12] + p[13]) + (p[14] + p[15]);
                l_s += (s0 + s1) + (s2 + s3);
            }

            half8 pa[2];
            #pragma unroll
            for (int c = 0; c < 2; ++c) {
                uint32_t u0 = pk16(p[8*c+0], p[8*c+1]);
                uint32_t u1 = pk16(p[8*c+2], p[8*c+3]);
                uint32_t u2 = pk16(p[8*c+4], p[8*c+5]);
                uint32_t u3 = pk16(p[8*c+6], p[8*c+7]);
                uint4v fw;
#if __has_builtin(__builtin_amdgcn_permlane32_swap)
                auto w02 = __builtin_amdgcn_permlane32_swap(u0, u2, false, false);
                auto w13 = __builtin_amdgcn_permlane32_swap(u1, u3, false, false);
                fw[0] = (uint32_t)w02[0]; fw[2] = (uint32_t)w02[1];
                fw[1] = (uint32_t)w13[0]; fw[3] = (uint32_t)w13[1];
#else
                uint32_t x0 = (uint32_t)__shfl_xor((int)u0, 32);
                uint32_t x1 = (uint32_t)__shfl_xor((int)u1, 32);
                uint32_t x2 = (uint32_t)__shfl_xor((int)u2, 32);
                uint32_t x3 = (uint32_t)__shfl_xor((int)u3, 32);
                if (hi == 0) { fw[0] = u0; fw[1] = u1; fw[2] = x0; fw[3] = x1; }
                else         { fw[0] = x2; fw[1] = x3; fw[2] = u2; fw[3] = u3; }
#endif
                pa[c] = __builtin_bit_cast(half8, fw);
            }

            #pragma unroll
            for (int db = 0; db < 4; ++db)
                #pragma unroll
                for (int c = 0; c < 2; ++c) {
                    half8 vb8 = *reinterpret_cast<const half8*>(
                        vsb + (2 * c + hi) * 2048 + (db * 32 + qn) * 16);
                    oacc[db] = __builtin_amdgcn_mfma_f32_32x32x16_f16(pa[c], vb8, oacc[db], 0, 0, 0);
                }
        }

        if (hl) V_WRITE(vsL, nxt, vl0, vl1);
        if (hh) V_WRITE(vsH, nxt, vh0, vh1);
    }

    l_s += __shfl_xor(l_s, 32);
    __syncthreads();

    if (hseg == 1) {
        float* mo = mrg_o + (size_t)(qsel * 64 + lane) * 68;
        #pragma unroll
        for (int db = 0; db < 4; ++db)
            #pragma unroll
            for (int r = 0; r < 16; ++r) mo[db * 16 + r] = oacc[db][r];
        mrg_ml[(qsel * 64 + lane) * 2 + 0] = m_s;
        mrg_ml[(qsel * 64 + lane) * 2 + 1] = l_s;
    }
    __syncthreads();
    if (hseg == 0) {
        float m1 = mrg_ml[(qsel * 64 + lane) * 2 + 0];
        float l1 = mrg_ml[(qsel * 64 + lane) * 2 + 1];
        float mm = fmaxf(m_s, m1);
        float e0 = fexp2(m_s - mm);
        float e1 = fexp2(m1 - mm);
        float inv = 1.f / (l_s * e0 + l1 * e1);
        float sc0 = e0 * inv, sc1 = e1 * inv;
        const float* mo = mrg_o + (size_t)(qsel * 64 + lane) * 68;
        #pragma unroll
        for (int r = 0; r < 16; ++r) {
            int qr = (r & 3) + 8 * (r >> 2) + 4 * hi;
            float s0r = __shfl(sc0, qr);
            float s1r = __shfl(sc1, qr);
            float* orow = Oh + ((size_t)(q0 + qr) << 7) + qn;
            #pragma unroll
            for (int db = 0; db < 4; ++db)
                orow[db * 32] = oacc[db][r] * s0r + mo[db * 16 + r] * s1r;
        }
    }
}

// ================= ABLATION variants (REP=2, write d_ws) =====================
// V=1: no softmax (mask/max/vote/rescale/exp/l removed)
// V=2: no PV (pa kept alive; V ds_reads + PV MFMAs removed)
// V=3: no QK^T MFMA (K ds_reads kept alive; sacc synthesized)
template<int VAR>
__global__ __launch_bounds__(512, 2) void swa_abl(
    const float* __restrict__ Q, const float* __restrict__ K,
    const float* __restrict__ V, float* __restrict__ O)
{
    __shared__ __align__(16) char arena[71680];
    char* ksL = arena;
    char* vsL = arena + 16384;
    char* ksH = arena + 32768;
    char* vsH = arena + 49152;
    float* mrg_o  = (float*)arena;
    float* mrg_ml = (float*)(arena + 69632);

    int bid = blockIdx.x;
    int wid = ((bid & 7) << 5) | (bid >> 3);
    int h    = wid >> 4;
    int q0wg = (wid & 15) << 7;

    int tid  = threadIdx.x;
    int wv   = tid >> 6;
    int lane = tid & 63;
    int qn = lane & 31;
    int hi = lane >> 5;
    int qsel = wv & 3;
    int hseg = wv >> 2;
    int q0 = q0wg + qsel * 32;

    const float* Qh = Q + ((size_t)h << 18);
    const float* Kg = K + ((size_t)h << 18);
    const float* Vg = V + ((size_t)h << 18);
    float*       Oh = O + ((size_t)h << 18);

    int tK_r = tid >> 4;
    int tK_d = (tid & 15) * 8;
    int tK_byte = tK_r * 256 + (((tid & 15) * 16) ^ ((tK_r & 7) << 4));
    int tV_d = (tid >> 4) * 4;
    int tV_s = (tid & 15) * 2;
    int tV_byte = (tV_s >> 3) * 2048 + tV_d * 16 + (tV_s & 7) * 2;

    half8 qa[8];
    const float* qrow = Qh + ((size_t)(q0 + qn) << 7) + hi * 8;
    #pragma unroll
    for (int c = 0; c < 8; ++c) {
        float4 a0 = *reinterpret_cast<const float4*>(qrow + c * 16);
        float4 a1 = *reinterpret_cast<const float4*>(qrow + c * 16 + 4);
        qa[c] = (half8){(_Float16)(a0.x * LOG2E), (_Float16)(a0.y * LOG2E),
                        (_Float16)(a0.z * LOG2E), (_Float16)(a0.w * LOG2E),
                        (_Float16)(a1.x * LOG2E), (_Float16)(a1.y * LOG2E),
                        (_Float16)(a1.z * LOG2E), (_Float16)(a1.w * LOG2E)};
    }

    f32x16 oacc[4];
    #pragma unroll
    for (int db = 0; db < 4; ++db)
        #pragma unroll
        for (int i = 0; i < 16; ++i) oacc[db][i] = 0.f;
    float m_s = -1e30f, l_s = 0.f;

    int kstart = q0wg - (WIN - 1);
    if (kstart < 0) kstart = 0;
    kstart &= ~31;
    int nt  = ((q0wg + 128) - kstart) >> 5;
    int nt0 = (nt + 1) >> 1;
    int ntH = nt - nt0;
    int iq   = q0 + qn;
    int w_ks = q0 - (WIN - 1);
    int w_ke = q0 + 32;
    int my_cnt = hseg ? ntH : nt0;

    for (int rep = 0; rep < 2; ++rep) {           // accumulators carry across
        {                                         // reps -> both reps live
            float4 a0, a1;
            K_LOAD(a0, a1, kstart);             K_WRITE(ksL, 0, a0, a1);
            K_LOAD(a0, a1, kstart + nt0 * 32);  K_WRITE(ksH, 0, a0, a1);
            V_LOAD(a0, a1, kstart);             V_WRITE(vsL, 0, a0, a1);
            V_LOAD(a0, a1, kstart + nt0 * 32);  V_WRITE(vsH, 0, a0, a1);
        }

        for (int it = 0; it < nt0; ++it) {
            int cur = it & 1, nxt = cur ^ 1;
            __syncthreads();

            bool hl = (it + 1 < nt0), hh = (it + 1 < ntH);
            float4 kl0, kl1, kh0, kh1;
            if (hl) K_LOAD(kl0, kl1, kstart + (it + 1) * 32);
            if (hh) K_LOAD(kh0, kh1, kstart + (nt0 + it + 1) * 32);

            int mt = (hseg ? nt0 : 0) + it;
            int kb = kstart + mt * 32;
            bool act = (it < my_cnt) && (kb < w_ke) && (kb + 32 > w_ks);
            const char* ksb = (hseg ? ksH : ksL) + cur * 8192;
            const char* vsb = (hseg ? vsH : vsL) + cur * 8192;

            f32x16 sacc;
            if (act) {
                int sw = (qn & 7) << 4;
                if constexpr (VAR == 3) {
                    #pragma unroll
                    for (int c = 0; c < 8; ++c) {
                        uint4v kw = *reinterpret_cast<const uint4v*>(
                            ksb + qn * 256 + ((c * 32 + hi * 16) ^ sw));
                        asm volatile("" :: "v"(kw[0]), "v"(kw[1]), "v"(kw[2]), "v"(kw[3]));
                    }
                    #pragma unroll
                    for (int i = 0; i < 16; ++i)
                        sacc[i] = (float)((i * 5 + qn + hi * 3) & 31) * 0.25f - 4.f;
                } else {
                    #pragma unroll
                    for (int i = 0; i < 16; ++i) sacc[i] = 0.f;
                    #pragma unroll
                    for (int c = 0; c < 8; ++c) {
                        half8 kh = *reinterpret_cast<const half8*>(
                            ksb + qn * 256 + ((c * 32 + hi * 16) ^ sw));
                        sacc = __builtin_amdgcn_mfma_f32_32x32x16_f16(kh, qa[c], sacc, 0, 0, 0);
                    }
                }
            }

            if (hl) K_WRITE(ksL, nxt, kl0, kl1);
            if (hh) K_WRITE(ksH, nxt, kh0, kh1);
            float4 vl0, vl1, vh0, vh1;
            if (hl) V_LOAD(vl0, vl1, kstart + (it + 1) * 32);
            if (hh) V_LOAD(vh0, vh1, kstart + (nt0 + it + 1) * 32);

            if (act) {
                float p[16];
                if constexpr (VAR == 1) {
                    #pragma unroll
                    for (int r = 0; r < 16; ++r) p[r] = sacc[r] * 0.1f;
                    l_s += p[0];
                } else {
                    bool fullt = (kb >= q0 - 480) && (kb <= q0 - 31);
                    if (fullt) {
                        #pragma unroll
                        for (int r = 0; r < 16; ++r) p[r] = sacc[r];
                    } else {
                        #pragma unroll
                        for (int r = 0; r < 16; ++r) {
                            int j = kb + (r & 3) + 8 * (r >> 2) + 4 * hi;
                            p[r] = ((j <= iq) && (j + WIN > iq)) ? sacc[r] : -1e30f;
                        }
                    }
                    float t0 = fmaxf(fmaxf(p[0], p[1]), p[2]);
                    float t1 = fmaxf(fmaxf(p[3], p[4]), p[5]);
                    float t2 = fmaxf(fmaxf(p[6], p[7]), p[8]);
                    float t3 = fmaxf(fmaxf(p[9], p[10]), p[11]);
                    float t4 = fmaxf(fmaxf(p[12], p[13]), p[14]);
                    float tm = fmaxf(fmaxf(fmaxf(t0, t1), fmaxf(t2, t3)), fmaxf(t4, p[15]));
                    tm = fmaxf(tm, __shfl_xor(tm, 32));
                    if (!__all(tm - m_s <= 11.5424f)) {
                        float mn = fmaxf(m_s, tm);
                        float scale = fexp2(m_s - mn);
                        m_s = mn;
                        l_s *= scale;
                        #pragma unroll
                        for (int r = 0; r < 16; ++r) {
                            float sr = __shfl(scale, (r & 3) + 8 * (r >> 2) + 4 * hi);
                            oacc[0][r] *= sr; oacc[1][r] *= sr;
                            oacc[2][r] *= sr; oacc[3][r] *= sr;
                        }
                    }
                    #pragma unroll
                    for (int r = 0; r < 16; ++r) p[r] = fexp2(p[r] - m_s);
                    float s0 = (p[0] + p[1]) + (p[2] + p[3]);
                    float s1 = (p[4] + p[5]) + (p[6] + p[7]);
                    float s2 = (p[8] + p[9]) + (p[10] + p[11]);
                    float s3 = (p[12] + p[13]) + (p[14] + p[15]);
                    l_s += (s0 + s1) + (s2 + s3);
                }

                half8 pa[2];
                #pragma unroll
                for (int c = 0; c < 2; ++c) {
                    uint32_t u0 = pk16(p[8*c+0], p[8*c+1]);
                    uint32_t u1 = pk16(p[8*c+2], p[8*c+3]);
                    uint32_t u2 = pk16(p[8*c+4], p[8*c+5]);
                    uint32_t u3 = pk16(p[8*c+6], p[8*c+7]);
                    uint4v fw;
#if __has_builtin(__builtin_amdgcn_permlane32_swap)
                    auto w02 = __builtin_amdgcn_permlane32_swap(u0, u2, false, false);
                    auto w13 = __builtin_amdgcn_permlane32_swap(u1, u3, false, false);
                    fw[0] = (uint32_t)w02[0]; fw[2] = (uint32_t)w02[1];
                    fw[1] = (uint32_t)w13[0]; fw[3] = (uint32_t)w13[1];
#else
                    uint32_t x0 = (uint32_t)__shfl_xor((int)u0, 32);
                    uint32_t x1 = (uint32_t)__shfl_xor((int)u1, 32);
                    uint32_t x2 = (uint32_t)__shfl_xor((int)u2, 32);
                    uint32_t x3 = (uint32_t)__shfl_xor((int)u3, 32);
                    if (hi == 0) { fw[0] = u0; fw[1] = u1; fw[2] = x0; fw[3] = x1; }
                    else         { fw[0] = x2; fw[1] = x3; fw[2] = u2; fw[3] = u3; }
#endif
                    pa[c] = __builtin_bit_cast(half8, fw);
                }

                if constexpr (VAR == 2) {
                    #pragma unroll
                    for (int c = 0; c < 2; ++c) {
                        uint4v w = __builtin_bit_cast(uint4v, pa[c]);
                        asm volatile("" :: "v"(w[0]), "v"(w[1]), "v"(w[2]), "v"(w[3]));
                    }
                    oacc[0][0] += p[15];   // keep oacc iteration-dependent
                } else {
                    #pragma unroll
                    for (int db = 0; db < 4; ++db)
                        #pragma unroll
                        for (int c = 0; c < 2; ++c) {
                            half8 vb8 = *reinterpret_cast<const half8*>(
                                vsb + (2 * c + hi) * 2048 + (db * 32 + qn) * 16);
                            oacc[db] = __builtin_amdgcn_mfma_f32_32x32x16_f16(pa[c], vb8, oacc[db], 0, 0, 0);
                        }
                }
            }

            if (hl) V_WRITE(vsL, nxt, vl0, vl1);
            if (hh) V_WRITE(vsH, nxt, vh0, vh1);
        }
        __syncthreads();   // inter-rep: all reads of last buf done before restage
    }

    l_s += __shfl_xor(l_s, 32);
    __syncthreads();

    if (hseg == 1) {
        float* mo = mrg_o + (size_t)(qsel * 64 + lane) * 68;
        #pragma unroll
        for (int db = 0; db < 4; ++db)
            #pragma unroll
            for (int r = 0; r < 16; ++r) mo[db * 16 + r] = oacc[db][r];
        mrg_ml[(qsel * 64 + lane) * 2 + 0] = m_s;
        mrg_ml[(qsel * 64 + lane) * 2 + 1] = l_s;
    }
    __syncthreads();
    if (hseg == 0) {
        float m1 = mrg_ml[(qsel * 64 + lane) * 2 + 0];
        float l1 = mrg_ml[(qsel * 64 + lane) * 2 + 1];
        float mm = fmaxf(m_s, m1);
        float e0 = fexp2(m_s - mm);
        float e1 = fexp2(m1 - mm);
        float inv = 1.f / (l_s * e0 + l1 * e1 + 1e-30f);
        float sc0 = e0 * inv, sc1 = e1 * inv;
        const float* mo = mrg_o + (size_t)(qsel * 64 + lane) * 68;
        #pragma unroll
        for (int r = 0; r < 16; ++r) {
            int qr = (r & 3) + 8 * (r >> 2) + 4 * hi;
            float s0r = __shfl(sc0, qr);
            float s1r = __shfl(sc1, qr);
            float* orow = Oh + ((size_t)(q0 + qr) << 7) + qn;
            #pragma unroll
            for (int db = 0; db < 4; ++db)
                orow[db * 32] = oacc[db][r] * s0r + mo[db * 16 + r] * s1r;
        }
    }
#undef K_LOAD
#undef K_WRITE
#undef V_LOAD
#undef V_WRITE
}

extern "C" void kernel_launch(void* const* d_in, const int* in_sizes, int n_in,
                              void* d_out, int out_size, void* d_ws, size_t ws_size,
                              hipStream_t stream) {
    (void)in_sizes; (void)n_in; (void)out_size; (void)ws_size;
    const float* q = (const float*)d_in[0];
    const float* k = (const float*)d_in[1];
    const float* v = (const float*)d_in[2];
    float* o  = (float*)d_out;
    float* ws = (float*)d_ws;   // ablation variants dump here (>=16.8MB, have 25MB)

    hipLaunchKernelGGL(swa_fwd, dim3(NWG), dim3(512), 0, stream, q, k, v, o);
    hipLaunchKernelGGL(swa_abl<1>, dim3(NWG), dim3(512), 0, stream, q, k, v, ws); // no softmax
    hipLaunchKernelGGL(swa_abl<2>, dim3(NWG), dim3(512), 0, stream, q, k, v, ws); // no PV
    hipLaunchKernelGGL(swa_abl<3>, dim3(NWG), dim3(512), 0, stream, q, k, v, ws); // no QK^T MFMA
}

// Round 20
// 67.386 us; speedup vs baseline: 2.2734x; 2.2734x over previous
//
#include <hip/hip_runtime.h>
#include <hip/hip_bf16.h>
#include <stdint.h>

#define H_NUM 16
#define S_LEN 2048
#define D_DIM 128
#define WIN   512
#define NWG   256                       // 16 heads x 16 q-groups(128 rows)
#define LOG2E 1.4426950408889634f

typedef __attribute__((ext_vector_type(8)))  _Float16 half8;
typedef __attribute__((ext_vector_type(2)))  __fp16   fp16x2;
typedef __attribute__((ext_vector_type(16))) float f32x16;
typedef __attribute__((ext_vector_type(4)))  unsigned int uint4v;

static __device__ __forceinline__ uint32_t pk16(float a, float b) {
    fp16x2 t = __builtin_amdgcn_cvt_pkrtz(a, b);
    return __builtin_bit_cast(uint32_t, t);
}
static __device__ __forceinline__ float fexp2(float x) {
#if __has_builtin(__builtin_amdgcn_exp2f)
    return __builtin_amdgcn_exp2f(x);
#else
    return exp2f(x);
#endif
}

// ---- flash SWA, r14 staging skeleton + r20 cross-iteration pipeline:
// finish(prev tile: softmax+PV from regs) fused into the same basic block as
// QK^T(cur tile) -> scheduler interleaves the serial chain that r19's ablation
// identified as the cost (each of QKT/SM/PV marginal ~= chain excess).
// V(prev) lives in registers (read during its own iteration under barrier
// protection -> no LDS WAR race). Unconditional rescale + branchless mask keep
// the fused block straight-line.
// 8 waves/WG = 4 q-tiles(32) x 2 window-halves; 32x32 MFMA; 1 barrier/iter.
// mfma_f32_32x32x16_f16: A row=lane&31,k=(lane>>5)*8+e; B col=lane&31,same k;
// C/D col=lane&31, row=(reg&3)+8*(reg>>2)+4*(lane>>5).
__global__ __launch_bounds__(512, 2) void swa_fwd(
    const float* __restrict__ Q, const float* __restrict__ K,
    const float* __restrict__ V, float* __restrict__ O)
{
    __shared__ __align__(16) char arena[71680];
    char* ksL = arena;                          // [2][8192] K low
    char* vsL = arena + 16384;                  // [2][8192] V low
    char* ksH = arena + 32768;                  // [2][8192] K high
    char* vsH = arena + 49152;                  // [2][8192] V high
    float* mrg_o  = (float*)arena;              // [4][64][68] (post-loop alias)
    float* mrg_ml = (float*)(arena + 69632);    // [4][64][2]

    int bid = blockIdx.x;
    int wid = ((bid & 7) << 5) | (bid >> 3);    // XCD-bijective (256%8==0)
    int h    = wid >> 4;
    int q0wg = (wid & 15) << 7;

    int tid  = threadIdx.x;
    int wv   = tid >> 6;
    int lane = tid & 63;
    int qn = lane & 31;
    int hi = lane >> 5;
    int qsel = wv & 3;
    int hseg = wv >> 2;
    int q0 = q0wg + qsel * 32;

    const float* Qh = Q + ((size_t)h << 18);
    const float* Kg = K + ((size_t)h << 18);
    const float* Vg = V + ((size_t)h << 18);
    float*       Oh = O + ((size_t)h << 18);

    int tK_r = tid >> 4;
    int tK_d = (tid & 15) * 8;
    int tK_byte = tK_r * 256 + (((tid & 15) * 16) ^ ((tK_r & 7) << 4));
    int tV_d = (tid >> 4) * 4;
    int tV_s = (tid & 15) * 2;
    int tV_byte = (tV_s >> 3) * 2048 + tV_d * 16 + (tV_s & 7) * 2;

#define K_LOAD(A0, A1, KB_) do {                                               \
        const float* sp_ = Kg + ((size_t)((KB_) + tK_r) << 7) + tK_d;          \
        A0 = *reinterpret_cast<const float4*>(sp_);                            \
        A1 = *reinterpret_cast<const float4*>(sp_ + 4); } while (0)
#define K_WRITE(KS, BUF, A0, A1) do {                                          \
        uint4v u_;                                                             \
        u_[0] = pk16(A0.x, A0.y); u_[1] = pk16(A0.z, A0.w);                    \
        u_[2] = pk16(A1.x, A1.y); u_[3] = pk16(A1.z, A1.w);                    \
        *reinterpret_cast<uint4v*>((KS) + (BUF) * 8192 + tK_byte) = u_; } while (0)
#define V_LOAD(A0, A1, KB_) do {                                               \
        const float* sp_ = Vg + ((size_t)((KB_) + tV_s) << 7) + tV_d;          \
        A0 = *reinterpret_cast<const float4*>(sp_);                            \
        A1 = *reinterpret_cast<const float4*>(sp_ + D_DIM); } while (0)
#define V_WRITE(VS, BUF, A0, A1) do {                                          \
        char* b_ = (VS) + (BUF) * 8192 + tV_byte;                              \
        *reinterpret_cast<uint32_t*>(b_)      = pk16(A0.x, A1.x);              \
        *reinterpret_cast<uint32_t*>(b_ + 16) = pk16(A0.y, A1.y);              \
        *reinterpret_cast<uint32_t*>(b_ + 32) = pk16(A0.z, A1.z);              \
        *reinterpret_cast<uint32_t*>(b_ + 48) = pk16(A0.w, A1.w); } while (0)

    // Q fragments, pre-scaled by log2e (exp2-domain softmax)
    half8 qa[8];
    const float* qrow = Qh + ((size_t)(q0 + qn) << 7) + hi * 8;
    #pragma unroll
    for (int c = 0; c < 8; ++c) {
        float4 a0 = *reinterpret_cast<const float4*>(qrow + c * 16);
        float4 a1 = *reinterpret_cast<const float4*>(qrow + c * 16 + 4);
        qa[c] = (half8){(_Float16)(a0.x * LOG2E), (_Float16)(a0.y * LOG2E),
                        (_Float16)(a0.z * LOG2E), (_Float16)(a0.w * LOG2E),
                        (_Float16)(a1.x * LOG2E), (_Float16)(a1.y * LOG2E),
                        (_Float16)(a1.z * LOG2E), (_Float16)(a1.w * LOG2E)};
    }

    f32x16 oacc[4];
    #pragma unroll
    for (int db = 0; db < 4; ++db)
        #pragma unroll
        for (int i = 0; i < 16; ++i) oacc[db][i] = 0.f;
    float m_s = -1e30f, l_s = 0.f;

    int kstart = q0wg - (WIN - 1);
    if (kstart < 0) kstart = 0;
    kstart &= ~31;
    int nt  = ((q0wg + 128) - kstart) >> 5;
    int nt0 = (nt + 1) >> 1;
    int ntH = nt - nt0;
    int iq   = q0 + qn;
    int w_ks = q0 - (WIN - 1);
    int w_ke = q0 + 32;

    // ---- pipeline state: prev tile's scores + V fragments (registers) ----
    f32x16 saccP;
    #pragma unroll
    for (int i = 0; i < 16; ++i) saccP[i] = 0.f;
    half8 vrP[8];
    #pragma unroll
    for (int i = 0; i < 8; ++i) vrP[i] = (half8)(_Float16)0.f;
    bool actP = false;
    int  kbP  = 0;

    // QK^T cur -> saccP (WAR reuse: FINISH reads old saccP first, same BB)
    auto QKT = [&](const char* ksb) {
        #pragma unroll
        for (int i = 0; i < 16; ++i) saccP[i] = 0.f;
        int sw = (qn & 7) << 4;
        #pragma unroll
        for (int c = 0; c < 8; ++c) {
            half8 kh = *reinterpret_cast<const half8*>(
                ksb + qn * 256 + ((c * 32 + hi * 16) ^ sw));
            saccP = __builtin_amdgcn_mfma_f32_32x32x16_f16(kh, qa[c], saccP, 0, 0, 0);
        }
    };
    // V(cur) -> registers (buf[cur] stable this iteration; reads drained by
    // the next barrier before any wave overwrites it)
    auto VR = [&](const char* vsb) {
        #pragma unroll
        for (int db = 0; db < 4; ++db)
            #pragma unroll
            for (int c = 0; c < 2; ++c)
                vrP[db * 2 + c] = *reinterpret_cast<const half8*>(
                    vsb + (2 * c + hi) * 2048 + (db * 32 + qn) * 16);
    };
    // finish prev tile: branchless mask + softmax (unconditional rescale) + PV
    auto FINISH = [&]() {
        float p[16];
        #pragma unroll
        for (int r = 0; r < 16; ++r) {
            int j = kbP + (r & 3) + 8 * (r >> 2) + 4 * hi;
            p[r] = ((j <= iq) && (j + WIN > iq)) ? saccP[r] : -1e30f;
        }
        float t0 = fmaxf(fmaxf(p[0], p[1]), p[2]);
        float t1 = fmaxf(fmaxf(p[3], p[4]), p[5]);
        float t2 = fmaxf(fmaxf(p[6], p[7]), p[8]);
        float t3 = fmaxf(fmaxf(p[9], p[10]), p[11]);
        float t4 = fmaxf(fmaxf(p[12], p[13]), p[14]);
        float tm = fmaxf(fmaxf(fmaxf(t0, t1), fmaxf(t2, t3)), fmaxf(t4, p[15]));
        tm = fmaxf(tm, __shfl_xor(tm, 32));

        float mn = fmaxf(m_s, tm);
        float scale = fexp2(m_s - mn);   // 0 wipes fresh-lane junk
        m_s = mn;
        l_s *= scale;
        #pragma unroll
        for (int r = 0; r < 16; ++r) {
            float sr = __shfl(scale, (r & 3) + 8 * (r >> 2) + 4 * hi);
            oacc[0][r] *= sr; oacc[1][r] *= sr;
            oacc[2][r] *= sr; oacc[3][r] *= sr;
        }
        #pragma unroll
        for (int r = 0; r < 16; ++r) p[r] = fexp2(p[r] - m_s);
        {
            float s0 = (p[0] + p[1]) + (p[2] + p[3]);
            float s1 = (p[4] + p[5]) + (p[6] + p[7]);
            float s2 = (p[8] + p[9]) + (p[10] + p[11]);
            float s3 = (p[12] + p[13]) + (p[14] + p[15]);
            l_s += (s0 + s1) + (s2 + s3);
        }
        half8 pa[2];
        #pragma unroll
        for (int c = 0; c < 2; ++c) {
            uint32_t u0 = pk16(p[8*c+0], p[8*c+1]);
            uint32_t u1 = pk16(p[8*c+2], p[8*c+3]);
            uint32_t u2 = pk16(p[8*c+4], p[8*c+5]);
            uint32_t u3 = pk16(p[8*c+6], p[8*c+7]);
            uint4v fw;
#if __has_builtin(__builtin_amdgcn_permlane32_swap)
            auto w02 = __builtin_amdgcn_permlane32_swap(u0, u2, false, false);
            auto w13 = __builtin_amdgcn_permlane32_swap(u1, u3, false, false);
            fw[0] = (uint32_t)w02[0]; fw[2] = (uint32_t)w02[1];
            fw[1] = (uint32_t)w13[0]; fw[3] = (uint32_t)w13[1];
#else
            uint32_t x0 = (uint32_t)__shfl_xor((int)u0, 32);
            uint32_t x1 = (uint32_t)__shfl_xor((int)u1, 32);
            uint32_t x2 = (uint32_t)__shfl_xor((int)u2, 32);
            uint32_t x3 = (uint32_t)__shfl_xor((int)u3, 32);
            if (hi == 0) { fw[0] = u0; fw[1] = u1; fw[2] = x0; fw[3] = x1; }
            else         { fw[0] = x2; fw[1] = x3; fw[2] = u2; fw[3] = u3; }
#endif
            pa[c] = __builtin_bit_cast(half8, fw);
        }
        #pragma unroll
        for (int db = 0; db < 4; ++db)
            #pragma unroll
            for (int c = 0; c < 2; ++c)
                oacc[db] = __builtin_amdgcn_mfma_f32_32x32x16_f16(
                    pa[c], vrP[db * 2 + c], oacc[db], 0, 0, 0);
    };

    // prologue: stage tile 0 of both streams
    {
        float4 a0, a1;
        K_LOAD(a0, a1, kstart);             K_WRITE(ksL, 0, a0, a1);
        K_LOAD(a0, a1, kstart + nt0 * 32);  K_WRITE(ksH, 0, a0, a1);
        V_LOAD(a0, a1, kstart);             V_WRITE(vsL, 0, a0, a1);
        V_LOAD(a0, a1, kstart + nt0 * 32);  V_WRITE(vsH, 0, a0, a1);
    }

    int my_cnt = hseg ? ntH : nt0;
    for (int it = 0; it < nt0; ++it) {
        int cur = it & 1, nxt = cur ^ 1;
        __syncthreads();   // buf[cur] published; all prev reads drained

        bool hl = (it + 1 < nt0), hh = (it + 1 < ntH);
        float4 kl0, kl1, kh0, kh1;
        if (hl) K_LOAD(kl0, kl1, kstart + (it + 1) * 32);
        if (hh) K_LOAD(kh0, kh1, kstart + (nt0 + it + 1) * 32);

        int mt = (hseg ? nt0 : 0) + it;
        int kb = kstart + mt * 32;
        bool act = (it < my_cnt) && (kb < w_ke) && (kb + 32 > w_ks);
        const char* ksb = (hseg ? ksH : ksL) + cur * 8192;
        const char* vsb = (hseg ? vsH : vsL) + cur * 8192;

        if (act && actP) {
            // hot fused block: finish(prev) interleaves with QK^T(cur) stalls
            FINISH();
            QKT(ksb);
            VR(vsb);
            kbP = kb;
        } else {
            if (actP) FINISH();
            if (act) { QKT(ksb); VR(vsb); kbP = kb; }
        }
        actP = act;

        // staging: write next K tiles, load+write next V tiles
        if (hl) K_WRITE(ksL, nxt, kl0, kl1);
        if (hh) K_WRITE(ksH, nxt, kh0, kh1);
        float4 vl0, vl1, vh0, vh1;
        if (hl) V_LOAD(vl0, vl1, kstart + (it + 1) * 32);
        if (hh) V_LOAD(vh0, vh1, kstart + (nt0 + it + 1) * 32);
        if (hl) V_WRITE(vsL, nxt, vl0, vl1);
        if (hh) V_WRITE(vsH, nxt, vh0, vh1);
    }

    // drain the pipeline: finish the last active tile (register-only)
    if (actP) FINISH();

    l_s += __shfl_xor(l_s, 32);
    __syncthreads();   // final-iter LDS ops drained before arena alias

    // -------- merge halves (arena aliases dead staging LDS) --------
    if (hseg == 1) {
        float* mo = mrg_o + (size_t)(qsel * 64 + lane) * 68;
        #pragma unroll
        for (int db = 0; db < 4; ++db)
            #pragma unroll
            for (int r = 0; r < 16; ++r) mo[db * 16 + r] = oacc[db][r];
        mrg_ml[(qsel * 64 + lane) * 2 + 0] = m_s;
        mrg_ml[(qsel * 64 + lane) * 2 + 1] = l_s;
    }
    __syncthreads();
    if (hseg == 0) {
        float m1 = mrg_ml[(qsel * 64 + lane) * 2 + 0];
        float l1 = mrg_ml[(qsel * 64 + lane) * 2 + 1];
        float mm = fmaxf(m_s, m1);
        float e0 = fexp2(m_s - mm);
        float e1 = fexp2(m1 - mm);
        float inv = 1.f / (l_s * e0 + l1 * e1);
        float sc0 = e0 * inv, sc1 = e1 * inv;
        const float* mo = mrg_o + (size_t)(qsel * 64 + lane) * 68;
        #pragma unroll
        for (int r = 0; r < 16; ++r) {
            int qr = (r & 3) + 8 * (r >> 2) + 4 * hi;
            float s0r = __shfl(sc0, qr);
            float s1r = __shfl(sc1, qr);
            float* orow = Oh + ((size_t)(q0 + qr) << 7) + qn;
            #pragma unroll
            for (int db = 0; db < 4; ++db)
                orow[db * 32] = oacc[db][r] * s0r + mo[db * 16 + r] * s1r;
        }
    }
#undef K_LOAD
#undef K_WRITE
#undef V_LOAD
#undef V_WRITE
}

extern "C" void kernel_launch(void* const* d_in, const int* in_sizes, int n_in,
                              void* d_out, int out_size, void* d_ws, size_t ws_size,
                              hipStream_t stream) {
    (void)in_sizes; (void)n_in; (void)out_size; (void)d_ws; (void)ws_size;
    const float* q = (const float*)d_in[0];
    const float* k = (const float*)d_in[1];
    const float* v = (const float*)d_in[2];
    // d_in[3] = mask: structural (causal sliding window, W=512) — never read.
    float* o = (float*)d_out;
    hipLaunchKernelGGL(swa_fwd, dim3(NWG), dim3(512), 0, stream, q, k, v, o);
}

// Round 21
// 32.550 us; speedup vs baseline: 4.7064x; 2.0703x over previous
//
#include <hip/hip_runtime.h>
#include <hip/hip_bf16.h>
#include <stdint.h>

#define H_NUM 16
#define S_LEN 2048
#define D_DIM 128
#define WIN   512
#define NWG   256                       // 16 heads x 16 q-groups(128 rows)
#define LOG2E 1.4426950408889634f

typedef __attribute__((ext_vector_type(8)))  _Float16 half8;
typedef __attribute__((ext_vector_type(2)))  __fp16   fp16x2;
typedef __attribute__((ext_vector_type(16))) float f32x16;
typedef __attribute__((ext_vector_type(4)))  unsigned int uint4v;

static __device__ __forceinline__ uint32_t pk16(float a, float b) {
    fp16x2 t = __builtin_amdgcn_cvt_pkrtz(a, b);   // v_cvt_pkrtz_f16_f32
    return __builtin_bit_cast(uint32_t, t);
}
static __device__ __forceinline__ float fexp2(float x) {
#if __has_builtin(__builtin_amdgcn_exp2f)
    return __builtin_amdgcn_exp2f(x);
#else
    return exp2f(x);
#endif
}

// ---- FINAL champion (r14, 32.6us): single-kernel flash SWA with in-kernel
// fp32->fp16 K convert and V transpose during reg-staged LDS staging.
// 8 waves/WG = 4 q-tiles(32) x 2 window-halves; 32x32 MFMA; 1 barrier/iter.
// Session ledger: r15 KVBLK=64 (-68%, L2 thrash), r16 setprio (null),
// r17 T14 issue-early (null), r18 chain-split (null), r20 cross-iter
// pipeline (-106%, VGPR spill). r19 ablation: cost = serial QKT->SM->PV
// chain latency, not any single phase; structure is latency-plateaued.
// mfma_f32_32x32x16_f16: A row=lane&31,k=(lane>>5)*8+e; B col=lane&31,same k;
// C/D col=lane&31, row=(reg&3)+8*(reg>>2)+4*(lane>>5).
// K LDS [32][256B] XOR-swizzled both sides (G21); V LDS slot-major [4][128][16B].
__global__ __launch_bounds__(512, 2) void swa_fwd(
    const float* __restrict__ Q, const float* __restrict__ K,
    const float* __restrict__ V, float* __restrict__ O)
{
    __shared__ __align__(16) char arena[71680];
    char* ksL = arena;                          // [2][8192] K low
    char* vsL = arena + 16384;                  // [2][8192] V low
    char* ksH = arena + 32768;                  // [2][8192] K high
    char* vsH = arena + 49152;                  // [2][8192] V high
    float* mrg_o  = (float*)arena;              // [4][64][68] (post-loop alias)
    float* mrg_ml = (float*)(arena + 69632);    // [4][64][2]

    int bid = blockIdx.x;
    int wid = ((bid & 7) << 5) | (bid >> 3);    // XCD-bijective (256%8==0)
    int h    = wid >> 4;
    int q0wg = (wid & 15) << 7;

    int tid  = threadIdx.x;
    int wv   = tid >> 6;
    int lane = tid & 63;
    int qn = lane & 31;
    int hi = lane >> 5;
    int qsel = wv & 3;
    int hseg = wv >> 2;
    int q0 = q0wg + qsel * 32;

    const float* Qh = Q + ((size_t)h << 18);
    const float* Kg = K + ((size_t)h << 18);
    const float* Vg = V + ((size_t)h << 18);
    float*       Oh = O + ((size_t)h << 18);

    // staging thread maps (512 threads cover one 8KB fp16 tile per stream)
    int tK_r = tid >> 4;                        // K row 0..31
    int tK_d = (tid & 15) * 8;                  // K d0
    int tK_byte = tK_r * 256 + (((tid & 15) * 16) ^ ((tK_r & 7) << 4));
    int tV_d = (tid >> 4) * 4;                  // V d0 0..124
    int tV_s = (tid & 15) * 2;                  // V s0 0..30 (even)
    int tV_byte = (tV_s >> 3) * 2048 + tV_d * 16 + (tV_s & 7) * 2;

#define K_LOAD(A0, A1, KB_) do {                                               \
        const float* sp_ = Kg + ((size_t)((KB_) + tK_r) << 7) + tK_d;          \
        A0 = *reinterpret_cast<const float4*>(sp_);                            \
        A1 = *reinterpret_cast<const float4*>(sp_ + 4); } while (0)
#define K_WRITE(KS, BUF, A0, A1) do {                                          \
        uint4v u_;                                                             \
        u_[0] = pk16(A0.x, A0.y); u_[1] = pk16(A0.z, A0.w);                    \
        u_[2] = pk16(A1.x, A1.y); u_[3] = pk16(A1.z, A1.w);                    \
        *reinterpret_cast<uint4v*>((KS) + (BUF) * 8192 + tK_byte) = u_; } while (0)
#define V_LOAD(A0, A1, KB_) do {                                               \
        const float* sp_ = Vg + ((size_t)((KB_) + tV_s) << 7) + tV_d;          \
        A0 = *reinterpret_cast<const float4*>(sp_);                            \
        A1 = *reinterpret_cast<const float4*>(sp_ + D_DIM); } while (0)
#define V_WRITE(VS, BUF, A0, A1) do {                                          \
        char* b_ = (VS) + (BUF) * 8192 + tV_byte;                              \
        *reinterpret_cast<uint32_t*>(b_)      = pk16(A0.x, A1.x);              \
        *reinterpret_cast<uint32_t*>(b_ + 16) = pk16(A0.y, A1.y);              \
        *reinterpret_cast<uint32_t*>(b_ + 32) = pk16(A0.z, A1.z);              \
        *reinterpret_cast<uint32_t*>(b_ + 48) = pk16(A0.w, A1.w); } while (0)

    // Q fragments, pre-scaled by log2e (exp2-domain softmax)
    half8 qa[8];
    const float* qrow = Qh + ((size_t)(q0 + qn) << 7) + hi * 8;
    #pragma unroll
    for (int c = 0; c < 8; ++c) {
        float4 a0 = *reinterpret_cast<const float4*>(qrow + c * 16);
        float4 a1 = *reinterpret_cast<const float4*>(qrow + c * 16 + 4);
        qa[c] = (half8){(_Float16)(a0.x * LOG2E), (_Float16)(a0.y * LOG2E),
                        (_Float16)(a0.z * LOG2E), (_Float16)(a0.w * LOG2E),
                        (_Float16)(a1.x * LOG2E), (_Float16)(a1.y * LOG2E),
                        (_Float16)(a1.z * LOG2E), (_Float16)(a1.w * LOG2E)};
    }

    f32x16 oacc[4];
    #pragma unroll
    for (int db = 0; db < 4; ++db)
        #pragma unroll
        for (int i = 0; i < 16; ++i) oacc[db][i] = 0.f;
    float m_s = -1e30f, l_s = 0.f;

    int kstart = q0wg - (WIN - 1);
    if (kstart < 0) kstart = 0;
    kstart &= ~31;
    int nt  = ((q0wg + 128) - kstart) >> 5;
    int nt0 = (nt + 1) >> 1;
    int ntH = nt - nt0;                  // >= 1
    int iq   = q0 + qn;
    int w_ks = q0 - (WIN - 1);
    int w_ke = q0 + 32;

    // prologue: stage tile 0 of both streams (fp32 load -> cvt -> LDS)
    {
        float4 a0, a1;
        K_LOAD(a0, a1, kstart);             K_WRITE(ksL, 0, a0, a1);
        K_LOAD(a0, a1, kstart + nt0 * 32);  K_WRITE(ksH, 0, a0, a1);
        V_LOAD(a0, a1, kstart);             V_WRITE(vsL, 0, a0, a1);
        V_LOAD(a0, a1, kstart + nt0 * 32);  V_WRITE(vsH, 0, a0, a1);
    }

    int my_cnt = hseg ? ntH : nt0;
    for (int it = 0; it < nt0; ++it) {
        int cur = it & 1, nxt = cur ^ 1;
        __syncthreads();   // publishes buf[cur] writes; all prev reads drained

        bool hl = (it + 1 < nt0), hh = (it + 1 < ntH);   // WG-uniform
        // issue next-tile K loads early: latency hides under QK^T
        float4 kl0, kl1, kh0, kh1;
        if (hl) K_LOAD(kl0, kl1, kstart + (it + 1) * 32);
        if (hh) K_LOAD(kh0, kh1, kstart + (nt0 + it + 1) * 32);

        int mt = (hseg ? nt0 : 0) + it;
        int kb = kstart + mt * 32;
        bool act = (it < my_cnt) && (kb < w_ke) && (kb + 32 > w_ks);
        const char* ksb = (hseg ? ksH : ksL) + cur * 8192;
        const char* vsb = (hseg ? vsH : vsL) + cur * 8192;

        f32x16 sacc;
        if (act) {
            #pragma unroll
            for (int i = 0; i < 16; ++i) sacc[i] = 0.f;
            int sw = (qn & 7) << 4;
            #pragma unroll
            for (int c = 0; c < 8; ++c) {
                half8 kh = *reinterpret_cast<const half8*>(
                    ksb + qn * 256 + ((c * 32 + hi * 16) ^ sw));
                sacc = __builtin_amdgcn_mfma_f32_32x32x16_f16(kh, qa[c], sacc, 0, 0, 0);
            }
        }

        // write next K tiles (loads done by now); issue V loads for next tile
        if (hl) K_WRITE(ksL, nxt, kl0, kl1);
        if (hh) K_WRITE(ksH, nxt, kh0, kh1);
        float4 vl0, vl1, vh0, vh1;
        if (hl) V_LOAD(vl0, vl1, kstart + (it + 1) * 32);
        if (hh) V_LOAD(vh0, vh1, kstart + (nt0 + it + 1) * 32);

        if (act) {
            // mask (interior skip)
            float p[16];
            bool fullt = (kb >= q0 - 480) && (kb <= q0 - 31);
            if (fullt) {
                #pragma unroll
                for (int r = 0; r < 16; ++r) p[r] = sacc[r];
            } else {
                #pragma unroll
                for (int r = 0; r < 16; ++r) {
                    int j = kb + (r & 3) + 8 * (r >> 2) + 4 * hi;
                    p[r] = ((j <= iq) && (j + WIN > iq)) ? sacc[r] : -1e30f;
                }
            }
            // row max (max3 tree) + pair exchange
            float t0 = fmaxf(fmaxf(p[0], p[1]), p[2]);
            float t1 = fmaxf(fmaxf(p[3], p[4]), p[5]);
            float t2 = fmaxf(fmaxf(p[6], p[7]), p[8]);
            float t3 = fmaxf(fmaxf(p[9], p[10]), p[11]);
            float t4 = fmaxf(fmaxf(p[12], p[13]), p[14]);
            float tm = fmaxf(fmaxf(fmaxf(t0, t1), fmaxf(t2, t3)), fmaxf(t4, p[15]));
            tm = fmaxf(tm, __shfl_xor(tm, 32));

            // T13 defer-max, threshold 8*log2e (forced rescale wipes fresh-lane junk)
            if (!__all(tm - m_s <= 11.5424f)) {
                float mn = fmaxf(m_s, tm);
                float scale = fexp2(m_s - mn);
                m_s = mn;
                l_s *= scale;
                #pragma unroll
                for (int r = 0; r < 16; ++r) {
                    float sr = __shfl(scale, (r & 3) + 8 * (r >> 2) + 4 * hi);
                    oacc[0][r] *= sr; oacc[1][r] *= sr;
                    oacc[2][r] *= sr; oacc[3][r] *= sr;
                }
            }
            #pragma unroll
            for (int r = 0; r < 16; ++r) p[r] = fexp2(p[r] - m_s);
            {
                float s0 = (p[0] + p[1]) + (p[2] + p[3]);
                float s1 = (p[4] + p[5]) + (p[6] + p[7]);
                float s2 = (p[8] + p[9]) + (p[10] + p[11]);
                float s3 = (p[12] + p[13]) + (p[14] + p[15]);
                l_s += (s0 + s1) + (s2 + s3);
            }

            // P -> PV A-frags in-register (pk + partner exchange)
            half8 pa[2];
            #pragma unroll
            for (int c = 0; c < 2; ++c) {
                uint32_t u0 = pk16(p[8*c+0], p[8*c+1]);
                uint32_t u1 = pk16(p[8*c+2], p[8*c+3]);
                uint32_t u2 = pk16(p[8*c+4], p[8*c+5]);
                uint32_t u3 = pk16(p[8*c+6], p[8*c+7]);
                uint4v fw;
#if __has_builtin(__builtin_amdgcn_permlane32_swap)
                auto w02 = __builtin_amdgcn_permlane32_swap(u0, u2, false, false);
                auto w13 = __builtin_amdgcn_permlane32_swap(u1, u3, false, false);
                fw[0] = (uint32_t)w02[0]; fw[2] = (uint32_t)w02[1];
                fw[1] = (uint32_t)w13[0]; fw[3] = (uint32_t)w13[1];
#else
                uint32_t x0 = (uint32_t)__shfl_xor((int)u0, 32);
                uint32_t x1 = (uint32_t)__shfl_xor((int)u1, 32);
                uint32_t x2 = (uint32_t)__shfl_xor((int)u2, 32);
                uint32_t x3 = (uint32_t)__shfl_xor((int)u3, 32);
                if (hi == 0) { fw[0] = u0; fw[1] = u1; fw[2] = x0; fw[3] = x1; }
                else         { fw[0] = x2; fw[1] = x3; fw[2] = u2; fw[3] = u3; }
#endif
                pa[c] = __builtin_bit_cast(half8, fw);
            }

            // P @ V
            #pragma unroll
            for (int db = 0; db < 4; ++db)
                #pragma unroll
                for (int c = 0; c < 2; ++c) {
                    half8 vb8 = *reinterpret_cast<const half8*>(
                        vsb + (2 * c + hi) * 2048 + (db * 32 + qn) * 16);
                    oacc[db] = __builtin_amdgcn_mfma_f32_32x32x16_f16(pa[c], vb8, oacc[db], 0, 0, 0);
                }
        }

        // write next V tiles (loads covered by softmax+PV span)
        if (hl) V_WRITE(vsL, nxt, vl0, vl1);
        if (hh) V_WRITE(vsH, nxt, vh0, vh1);
    }

    l_s += __shfl_xor(l_s, 32);
    __syncthreads();   // final-iter LDS ops drained before arena alias

    // -------- merge halves (arena aliases dead staging LDS) --------
    if (hseg == 1) {
        float* mo = mrg_o + (size_t)(qsel * 64 + lane) * 68;
        #pragma unroll
        for (int db = 0; db < 4; ++db)
            #pragma unroll
            for (int r = 0; r < 16; ++r) mo[db * 16 + r] = oacc[db][r];
        mrg_ml[(qsel * 64 + lane) * 2 + 0] = m_s;
        mrg_ml[(qsel * 64 + lane) * 2 + 1] = l_s;
    }
    __syncthreads();
    if (hseg == 0) {
        float m1 = mrg_ml[(qsel * 64 + lane) * 2 + 0];
        float l1 = mrg_ml[(qsel * 64 + lane) * 2 + 1];
        float mm = fmaxf(m_s, m1);
        float e0 = fexp2(m_s - mm);
        float e1 = fexp2(m1 - mm);
        float inv = 1.f / (l_s * e0 + l1 * e1);
        float sc0 = e0 * inv, sc1 = e1 * inv;
        const float* mo = mrg_o + (size_t)(qsel * 64 + lane) * 68;
        #pragma unroll
        for (int r = 0; r < 16; ++r) {
            int qr = (r & 3) + 8 * (r >> 2) + 4 * hi;
            float s0r = __shfl(sc0, qr);
            float s1r = __shfl(sc1, qr);
            float* orow = Oh + ((size_t)(q0 + qr) << 7) + qn;
            #pragma unroll
            for (int db = 0; db < 4; ++db)
                orow[db * 32] = oacc[db][r] * s0r + mo[db * 16 + r] * s1r;
        }
    }
#undef K_LOAD
#undef K_WRITE
#undef V_LOAD
#undef V_WRITE
}

extern "C" void kernel_launch(void* const* d_in, const int* in_sizes, int n_in,
                              void* d_out, int out_size, void* d_ws, size_t ws_size,
                              hipStream_t stream) {
    (void)in_sizes; (void)n_in; (void)out_size; (void)d_ws; (void)ws_size;
    const float* q = (const float*)d_in[0];
    const float* k = (const float*)d_in[1];
    const float* v = (const float*)d_in[2];
    // d_in[3] = mask: structural (causal sliding window, W=512) — never read.
    float* o = (float*)d_out;
    hipLaunchKernelGGL(swa_fwd, dim3(NWG), dim3(512), 0, stream, q, k, v, o);
}